// Round 1
// baseline (322.284 us; speedup 1.0000x reference)
//
#include <hip/hip_runtime.h>

#define BB 64
#define NN 1024

// out layout (floats):
//   [0]                      done
//   [1 .. 1+B*N)             new_mask
//   [1+B*N .. 1+B*N+B*N*N)   adj
//   then future_actions[B], present_time_new[B], step_mask[B]
#define OFF_NM   1L
#define OFF_ADJ  (1L + (long)BB * NN)
#define OFF_FA   (OFF_ADJ + (long)BB * NN * NN)

// ws layout (floats): cl[B*N], du[B*N], nm[B*N], dlast[N]

__global__ __launch_bounds__(256) void kA(const float* __restrict__ inputs,
                                          const float* __restrict__ dist,
                                          const float* __restrict__ mask,
                                          const float* __restrict__ pt,
                                          const int*   __restrict__ pa,
                                          float* __restrict__ out,
                                          float* __restrict__ ws) {
    int gid = blockIdx.x * 256 + threadIdx.x;   // b*N + j
    int b = gid >> 10;
    int j = gid & (NN - 1);
    int p = pa[b];
    float ptb = pt[b];
    const float* row = inputs + (size_t)gid * 4;
    float op = row[0], cl = row[1], du = row[2];
    float tt = inputs[3];                        // inputs[0,0,ARR]
    float dl = dist[(size_t)j * NN + (NN - 1)];  // dlast[j]
    float arr = dist[(size_t)p * NN + j] + ptb;
    float w = fmaxf(0.0f, op - arr);
    float t = arr + w;
    bool c1 = (t <= cl);
    bool c2 = (((t + du) + dl) <= tt);
    float m = (j == p) ? 0.0f : mask[gid];
    float nm = (c1 && c2) ? m : 0.0f;
    out[OFF_NM + gid] = nm;
    ws[gid]               = cl;
    ws[BB * NN + gid]     = du;
    ws[2 * BB * NN + gid] = nm;
    if (b == 0) ws[3 * BB * NN + j] = dl;
}

__global__ __launch_bounds__(64) void kB(const float* __restrict__ inputs,
                                         const float* __restrict__ dist,
                                         const float* __restrict__ mask,
                                         const float* __restrict__ pt,
                                         const int*   __restrict__ pa,
                                         const int*   __restrict__ fa,
                                         float* __restrict__ out) {
    int b = threadIdx.x;   // 0..63
    int p = pa[b];
    float ptb = pt[b];
    // recompute new_mask[b, N-1] for the `done` reduction
    const float* row = inputs + (size_t)(b * NN + (NN - 1)) * 4;
    float op = row[0], cl = row[1], du = row[2];
    float tt = inputs[3];
    float dl = dist[(size_t)(NN - 1) * NN + (NN - 1)];
    float arr = dist[(size_t)p * NN + (NN - 1)] + ptb;
    float w = fmaxf(0.0f, op - arr);
    float t = arr + w;
    bool alive = (t <= cl) && (((t + du) + dl) <= tt);
    float m = ((NN - 1) == p) ? 0.0f : mask[b * NN + (NN - 1)];
    float nm = alive ? m : 0.0f;
    unsigned long long ball = __ballot(nm > 0.0f);
    if (b == 0) out[0] = (ball == 0ULL) ? 1.0f : 0.0f;

    int f = fa[b];
    float arrj = dist[(size_t)p * NN + f] + ptb;
    const float* frow = inputs + (size_t)(b * NN + f) * 4;
    float wj = fmaxf(0.0f, frow[0] - arrj);
    float ptn = (arrj + wj) + frow[2];
    out[OFF_FA + b]           = (float)f;
    out[OFF_FA + BB + b]      = ptn;
    out[OFF_FA + 2 * BB + b]  = 1.0f;
}

__global__ __launch_bounds__(256) void kC(const float* __restrict__ inputs,
                                          const float* __restrict__ dist,
                                          const float* __restrict__ pt,
                                          const int*   __restrict__ pa,
                                          const float* __restrict__ ws,
                                          float* __restrict__ out) {
    int blk = blockIdx.x;          // b*N + i
    int b = blk >> 10;
    int i = blk & (NN - 1);
    int p = pa[b];
    float ptb = pt[b];
    const float* irow = inputs + (size_t)blk * 4;
    float op_i = irow[0];
    float du_i = irow[2];
    float tt_b = inputs[(size_t)b * NN * 4 + 3];     // inputs[b,0,ARR]
    // fpresent[b,i] with exact reference op order:
    float arr_i = dist[(size_t)p * NN + i] + ptb;
    float w_i = fmaxf(0.0f, op_i - arr_i);
    float fp = (arr_i + w_i) + du_i;

    int j0 = threadIdx.x * 4;
    float4 d4  = *(const float4*)(dist + (size_t)i * NN + j0);
    float4 cl4 = *(const float4*)(ws + (size_t)b * NN + j0);
    float4 du4 = *(const float4*)(ws + (size_t)(BB * NN) + b * NN + j0);
    float4 nm4 = *(const float4*)(ws + (size_t)(2 * BB * NN) + b * NN + j0);
    float4 dl4 = *(const float4*)(ws + (size_t)(3 * BB * NN) + j0);

    float dv[4]  = {d4.x, d4.y, d4.z, d4.w};
    float clv[4] = {cl4.x, cl4.y, cl4.z, cl4.w};
    float duv[4] = {du4.x, du4.y, du4.z, du4.w};
    float nmv[4] = {nm4.x, nm4.y, nm4.z, nm4.w};
    float dlv[4] = {dl4.x, dl4.y, dl4.z, dl4.w};

    float* orow = out + OFF_ADJ + (size_t)blk * NN;
#pragma unroll
    for (int u = 0; u < 4; ++u) {
        int j = j0 + u;
        float arr2 = dv[u] + fp;
        float w2 = fmaxf(0.0f, op_i - arr2);
        float s = arr2 + w2;
        bool a1 = (s <= clv[u]);
        bool a2 = (((s + duv[u]) + dlv[u]) <= tt_b);
        float v = (a1 && a2) ? nmv[u] : 0.0f;
        if (j == i) v = 1.0f;
        __builtin_nontemporal_store(v, orow + j);
    }
}

extern "C" void kernel_launch(void* const* d_in, const int* in_sizes, int n_in,
                              void* d_out, int out_size, void* d_ws, size_t ws_size,
                              hipStream_t stream) {
    const float* inputs = (const float*)d_in[0];   // (B,N,4)
    const float* dist   = (const float*)d_in[1];   // (N,N)
    const float* mask   = (const float*)d_in[2];   // (B,N)
    const float* pt     = (const float*)d_in[3];   // (B,1)
    const int*   pa     = (const int*)d_in[4];     // (B,)
    const int*   fa     = (const int*)d_in[5];     // (B,)
    float* out = (float*)d_out;
    float* ws  = (float*)d_ws;

    kA<<<(BB * NN) / 256, 256, 0, stream>>>(inputs, dist, mask, pt, pa, out, ws);
    kB<<<1, 64, 0, stream>>>(inputs, dist, mask, pt, pa, fa, out);
    kC<<<BB * NN, 256, 0, stream>>>(inputs, dist, pt, pa, ws, out);
}

// Round 2
// 294.396 us; speedup vs baseline: 1.0947x; 1.0947x over previous
//
#include <hip/hip_runtime.h>

#define BB 64
#define NN 1024

// out layout (floats):
//   [0]                      done
//   [1 .. 1+B*N)             new_mask
//   [1+B*N .. 1+B*N+B*N*N)   adj
//   then future_actions[B], present_time_new[B], step_mask[B]
#define OFF_NM   1L
#define OFF_ADJ  (1L + (long)BB * NN)
#define OFF_FA   (OFF_ADJ + (long)BB * NN * NN)

// ws layout:
//   float4 pack[B*N]  = {cl, du, nm, dl}      bytes [0, 1 MB)
//   float2 rowsc[B*N] = {fpresent, opening}   bytes [1 MB, 1.5 MB)

__global__ __launch_bounds__(256) void kA(const float* __restrict__ inputs,
                                          const float* __restrict__ dist,
                                          const float* __restrict__ mask,
                                          const float* __restrict__ pt,
                                          const int*   __restrict__ pa,
                                          float* __restrict__ out,
                                          float4* __restrict__ pack,
                                          float2* __restrict__ rowsc) {
    int gid = blockIdx.x * 256 + threadIdx.x;   // b*N + j
    int b = gid >> 10;
    int j = gid & (NN - 1);
    int p = pa[b];
    float ptb = pt[b];
    const float* row = inputs + (size_t)gid * 4;
    float op = row[0], cl = row[1], du = row[2];
    float tt = inputs[3];                        // inputs[0,0,ARR]
    float dl = dist[(size_t)j * NN + (NN - 1)];  // dlast[j]
    float arr = dist[(size_t)p * NN + j] + ptb;  // arrive == farrive
    float w = fmaxf(0.0f, op - arr);
    float t = arr + w;
    bool c1 = (t <= cl);
    bool c2 = (((t + du) + dl) <= tt);
    float m = (j == p) ? 0.0f : mask[gid];
    float nm = (c1 && c2) ? m : 0.0f;
    float fp = t + du;                           // (farrive + fwait) + durat
    out[OFF_NM + gid] = nm;
    pack[gid]  = make_float4(cl, du, nm, dl);
    rowsc[gid] = make_float2(fp, op);
}

__global__ __launch_bounds__(64) void kB(const float* __restrict__ inputs,
                                         const float* __restrict__ dist,
                                         const float* __restrict__ mask,
                                         const float* __restrict__ pt,
                                         const int*   __restrict__ pa,
                                         const int*   __restrict__ fa,
                                         float* __restrict__ out) {
    int b = threadIdx.x;   // 0..63
    int p = pa[b];
    float ptb = pt[b];
    // recompute new_mask[b, N-1] for the `done` reduction
    const float* row = inputs + (size_t)(b * NN + (NN - 1)) * 4;
    float op = row[0], cl = row[1], du = row[2];
    float tt = inputs[3];
    float dl = dist[(size_t)(NN - 1) * NN + (NN - 1)];
    float arr = dist[(size_t)p * NN + (NN - 1)] + ptb;
    float w = fmaxf(0.0f, op - arr);
    float t = arr + w;
    bool alive = (t <= cl) && (((t + du) + dl) <= tt);
    float m = ((NN - 1) == p) ? 0.0f : mask[b * NN + (NN - 1)];
    float nm = alive ? m : 0.0f;
    unsigned long long ball = __ballot(nm > 0.0f);
    if (b == 0) out[0] = (ball == 0ULL) ? 1.0f : 0.0f;

    int f = fa[b];
    float arrj = dist[(size_t)p * NN + f] + ptb;
    const float* frow = inputs + (size_t)(b * NN + f) * 4;
    float wj = fmaxf(0.0f, frow[0] - arrj);
    float ptn = (arrj + wj) + frow[2];
    out[OFF_FA + b]           = (float)f;
    out[OFF_FA + BB + b]      = ptn;
    out[OFF_FA + 2 * BB + b]  = 1.0f;
}

__global__ __launch_bounds__(256) void kC(const float4* __restrict__ pack,
                                          const float2* __restrict__ rowsc,
                                          const float* __restrict__ inputs,
                                          const float* __restrict__ dist,
                                          float* __restrict__ out) {
    int blk = blockIdx.x;          // b*N + i
    int b = blk >> 10;
    int i = blk & (NN - 1);
    float2 r = rowsc[blk];         // wave-uniform
    float fp = r.x, op_i = r.y;
    float tt_b = inputs[(size_t)b * NN * 4 + 3];   // inputs[b,0,ARR]

    const float*  drow = dist + (size_t)i * NN;
    const float4* prow = pack + (size_t)b * NN;
    float* orow = out + OFF_ADJ + (size_t)blk * NN;
    int t = threadIdx.x;
#pragma unroll
    for (int u = 0; u < 4; ++u) {
        int j = t + u * 256;                       // lane-contiguous
        float  dv = drow[j];
        float4 pk = prow[j];                       // {cl, du, nm, dl}
        float arr2 = dv + fp;
        float w2 = fmaxf(0.0f, op_i - arr2);
        float s = arr2 + w2;
        bool a1 = (s <= pk.x);
        bool a2 = (((s + pk.y) + pk.w) <= tt_b);
        float v = (a1 && a2) ? pk.z : 0.0f;
        if (j == i) v = 1.0f;
        __builtin_nontemporal_store(v, orow + j);
    }
}

extern "C" void kernel_launch(void* const* d_in, const int* in_sizes, int n_in,
                              void* d_out, int out_size, void* d_ws, size_t ws_size,
                              hipStream_t stream) {
    const float* inputs = (const float*)d_in[0];   // (B,N,4)
    const float* dist   = (const float*)d_in[1];   // (N,N)
    const float* mask   = (const float*)d_in[2];   // (B,N)
    const float* pt     = (const float*)d_in[3];   // (B,1)
    const int*   pa     = (const int*)d_in[4];     // (B,)
    const int*   fa     = (const int*)d_in[5];     // (B,)
    float* out = (float*)d_out;
    float4* pack  = (float4*)d_ws;
    float2* rowsc = (float2*)((char*)d_ws + (size_t)BB * NN * sizeof(float4));

    kA<<<(BB * NN) / 256, 256, 0, stream>>>(inputs, dist, mask, pt, pa, out, pack, rowsc);
    kB<<<1, 64, 0, stream>>>(inputs, dist, mask, pt, pa, fa, out);
    kC<<<BB * NN, 256, 0, stream>>>(pack, rowsc, inputs, dist, out);
}